// Round 1
// baseline (147.280 us; speedup 1.0000x reference)
//
#include <hip/hip_runtime.h>

// out = A @ x, A sparse COO (rows sorted), E=800000, N=50000, D=128.
// Edge-parallel segmented reduction: each wave owns a contiguous edge range,
// lane l accumulates feature dims {2l,2l+1} in registers, flushing with
// atomicAdd only when the (sorted) row id changes.

#define D_FEAT 128
#define TOTAL_WAVES 8192
#define WAVES_PER_BLOCK 4
#define BLOCK_THREADS (WAVES_PER_BLOCK * 64)

__device__ __forceinline__ float bcast_f(float v, int j) {
    return __int_as_float(__builtin_amdgcn_readlane(__float_as_int(v), j));
}

__global__ __launch_bounds__(BLOCK_THREADS) void agg_kernel(
    const float* __restrict__ x, const float* __restrict__ vals,
    const int* __restrict__ rows, const int* __restrict__ cols,
    float* __restrict__ out, int n_edges, int epw) {
    const int wave = blockIdx.x * WAVES_PER_BLOCK + (threadIdx.x >> 6);
    const int lane = threadIdx.x & 63;

    const int start = wave * epw;
    if (start >= n_edges) return;
    int end = start + epw;
    if (end > n_edges) end = n_edges;

    const float2* __restrict__ x2 = (const float2*)x;

    float2 acc = make_float2(0.f, 0.f);
    int cur_row = rows[start];  // wave-uniform

    for (int e0 = start; e0 < end; e0 += 64) {
        const int nb = min(end - e0, 64);
        int   myc = 0;
        int   myr = cur_row;
        float myv = 0.f;
        if (lane < nb) {
            myc = cols[e0 + lane];
            myr = rows[e0 + lane];
            myv = vals[e0 + lane];
        }
        for (int j = 0; j < nb; ++j) {
            const int   rj = __builtin_amdgcn_readlane(myr, j);
            const int   cj = __builtin_amdgcn_readlane(myc, j);
            const float vj = bcast_f(myv, j);
            if (rj != cur_row) {  // wave-uniform branch (avg 1-in-16)
                float* o = out + (size_t)cur_row * D_FEAT + 2 * lane;
                atomicAdd(o,     acc.x);
                atomicAdd(o + 1, acc.y);
                acc.x = 0.f; acc.y = 0.f;
                cur_row = rj;
            }
            const float2 xv = x2[(size_t)cj * (D_FEAT / 2) + lane];
            acc.x += vj * xv.x;
            acc.y += vj * xv.y;
        }
    }
    float* o = out + (size_t)cur_row * D_FEAT + 2 * lane;
    atomicAdd(o,     acc.x);
    atomicAdd(o + 1, acc.y);
}

extern "C" void kernel_launch(void* const* d_in, const int* in_sizes, int n_in,
                              void* d_out, int out_size, void* d_ws, size_t ws_size,
                              hipStream_t stream) {
    const float* x    = (const float*)d_in[0];
    const float* vals = (const float*)d_in[1];
    const int*   rows = (const int*)d_in[2];
    const int*   cols = (const int*)d_in[3];
    float*       out  = (float*)d_out;

    const int n_edges = in_sizes[1];

    // Zero output (harness poisons it with 0xAA before every timed launch).
    hipMemsetAsync(d_out, 0, (size_t)out_size * sizeof(float), stream);

    const int epw = (n_edges + TOTAL_WAVES - 1) / TOTAL_WAVES;  // edges per wave
    const int blocks = TOTAL_WAVES / WAVES_PER_BLOCK;
    agg_kernel<<<blocks, BLOCK_THREADS, 0, stream>>>(x, vals, rows, cols, out,
                                                     n_edges, epw);
}